// Round 3
// baseline (3817.778 us; speedup 1.0000x reference)
//
#include <hip/hip_runtime.h>
#include <stdint.h>

#define D_DIM 512
#define SPLIT_K 384   // OpenBLAS sgemm kc (Haswell/ZEN SGEMM_DEFAULT_Q)

typedef unsigned long long u64;

// ---------------- init workspace (histogram only) ----------------
__global__ void k_init(int* __restrict__ counts, int K) {
  int i = blockIdx.x * blockDim.x + threadIdx.x;
  if (i < K) counts[i] = 0;
}

// ---------------- numpy-replicated row sum of squares ----------------
// np.sum(x*x, axis=1), replicating numpy pairwise sum with AVX512 base case
// (validated bit-exact in round 2: first check absmax 0.0)
__global__ void k_rowsq(const float* __restrict__ X, float* __restrict__ out, int nrows) {
  int t = threadIdx.x;
  int row = blockIdx.x * 4 + (t >> 6);
  int l = t & 63;
  if (row >= nrows) return;
  int b = l >> 4;   // 128-block index 0..3
  int L = l & 15;   // lane within the zmm vector
  const float* p = X + (size_t)row * D_DIM + b * 128 + L;
  float v[8];
#pragma unroll
  for (int j = 0; j < 8; ++j) {
    float x = p[16 * j];
    float sq = x * x;
    asm volatile("" : "+v"(sq));  // keep mul separate from sum (no fma contraction)
    v[j] = sq;
  }
  float s = ((v[0] + v[1]) + (v[2] + v[3])) + ((v[4] + v[5]) + (v[6] + v[7]));
  s += __shfl_xor(s, 8, 64);
  s += __shfl_xor(s, 4, 64);
  s += __shfl_xor(s, 2, 64);
  s += __shfl_xor(s, 1, 64);
  s += __shfl_xor(s, 16, 64);
  s += __shfl_xor(s, 32, 64);
  if (l == 0) out[row] = s;
}

// ---------------- fused GEMM + argmin over ALL K, block-local ----------------
// One block owns 128 rows; loops over all 64 column tiles, keeping the
// packed (scorebits,idx) min in registers. NO cross-block combining.
#define KTILE(D0, ACC)                                                          \
  {                                                                             \
    int r = t >> 2;                                                             \
    int c4 = (t & 3) << 2;                                                      \
    float4 va = *(const float4*)(A + (size_t)(m0 + r) * D_DIM + (D0) + c4);     \
    As[c4 + 0][r] = va.x; As[c4 + 1][r] = va.y;                                 \
    As[c4 + 2][r] = va.z; As[c4 + 3][r] = va.w;                                 \
    float4 vb = *(const float4*)(E + (size_t)(n0 + r) * D_DIM + (D0) + c4);     \
    Es[c4 + 0][r] = vb.x; Es[c4 + 1][r] = vb.y;                                 \
    Es[c4 + 2][r] = vb.z; Es[c4 + 3][r] = vb.w;                                 \
    __syncthreads();                                                            \
    _Pragma("unroll")                                                           \
    for (int dd = 0; dd < 16; ++dd) {                                           \
      float af[4], bf[8];                                                       \
      *(float4*)af = *(const float4*)(&As[dd][ty * 4]);                         \
      *(float4*)bf = *(const float4*)(&Es[dd][tx * 4]);                         \
      *(float4*)(bf + 4) = *(const float4*)(&Es[dd][64 + tx * 4]);              \
      _Pragma("unroll")                                                         \
      for (int i = 0; i < 4; ++i)                                               \
        _Pragma("unroll")                                                       \
        for (int j = 0; j < 8; ++j)                                             \
          ACC[i][j] = fmaf(af[i], bf[j], ACC[i][j]);                            \
    }                                                                           \
    __syncthreads();                                                            \
  }

__global__ __launch_bounds__(512) void k_argmin(
    const float* __restrict__ A, const float* __restrict__ E,
    const float* __restrict__ a2, const float* __restrict__ e2,
    float* __restrict__ out_idx, int* __restrict__ idx_ws, int K) {
  __shared__ float As[16][128];
  __shared__ float Es[16][128];
  const int m0 = blockIdx.x * 128;
  const int t = threadIdx.x;
  const int tx = t & 15;
  const int ty = t >> 4;   // 0..31 -> rows ty*4 .. ty*4+3

  float a2l[4];
#pragma unroll
  for (int i = 0; i < 4; ++i) a2l[i] = a2[m0 + ty * 4 + i];

  u64 best[4];
#pragma unroll
  for (int i = 0; i < 4; ++i) best[i] = ~0ULL;

  for (int n0 = 0; n0 < K; n0 += 128) {
    float acc1[4][8], acc2[4][8];
#pragma unroll
    for (int i = 0; i < 4; ++i)
#pragma unroll
      for (int j = 0; j < 8; ++j) { acc1[i][j] = 0.f; acc2[i][j] = 0.f; }

    for (int d0 = 0; d0 < SPLIT_K; d0 += 16) KTILE(d0, acc1)
    for (int d0 = SPLIT_K; d0 < D_DIM; d0 += 16) KTILE(d0, acc2)

    float e2l[8];
#pragma unroll
    for (int j = 0; j < 8; ++j) {
      int cl = (j < 4) ? (tx * 4 + j) : (64 + tx * 4 + (j - 4));
      e2l[j] = e2[n0 + cl];
    }
#pragma unroll
    for (int i = 0; i < 4; ++i) {
#pragma unroll
      for (int j = 0; j < 8; ++j) {
        int cl = (j < 4) ? (tx * 4 + j) : (64 + tx * 4 + (j - 4));
        float S = a2l[i] + e2l[j];            // fl(a2 + e2)
        float m = acc1[i][j] + acc2[i][j];    // fl(S1 + S2) = BLAS kc-split merge
        float s = fmaf(-2.f, m, S);           // fl(S - 2M), 2M exact
        unsigned u = __float_as_uint(s);
        u = (u & 0x80000000u) ? ~u : (u | 0x80000000u);  // monotone float->uint
        u64 p = ((u64)u << 32) | (unsigned)(n0 + cl);
        if (p < best[i]) best[i] = p;
      }
    }
  }

  // reduce across the 16 tx lanes sharing each row group (in-wave, aligned)
#pragma unroll
  for (int m = 1; m < 16; m <<= 1) {
#pragma unroll
    for (int i = 0; i < 4; ++i) {
      u64 o = __shfl_xor(best[i], m, 64);
      if (o < best[i]) best[i] = o;
    }
  }
  if (tx == 0) {
#pragma unroll
    for (int i = 0; i < 4; ++i) {
      int row = m0 + ty * 4 + i;
      int idx = (int)(unsigned)(best[i] & 0xFFFFFFFFULL);
      out_idx[row] = (float)idx;
      idx_ws[row] = idx;
    }
  }
}

// ---------------- gather z_q, write z, per-row loss partial, histogram ----------------
__global__ void k_gather(const float* __restrict__ A, const float* __restrict__ E,
                         const int* __restrict__ idx_ws,
                         float* __restrict__ out_z, float* __restrict__ rowsum,
                         int* __restrict__ counts) {
  int b = blockIdx.x;
  int t = threadIdx.x;  // 128 threads, float4 each = 512
  int idx = idx_ws[b];
  const float4* pa = (const float4*)(A + (size_t)b * D_DIM);
  const float4* pe = (const float4*)(E + (size_t)idx * D_DIM);
  float4 a = pa[t];
  float4 e = pe[t];
  float4 z;
  z.x = a.x + (e.x - a.x);  // replicate ref f32 ops exactly
  z.y = a.y + (e.y - a.y);
  z.z = a.z + (e.z - a.z);
  z.w = a.w + (e.w - a.w);
  ((float4*)(out_z + (size_t)b * D_DIM))[t] = z;
  float dx = a.x - e.x, dy = a.y - e.y, dz = a.z - e.z, dw = a.w - e.w;
  float ls = dx * dx + dy * dy + dz * dz + dw * dw;
#pragma unroll
  for (int off = 32; off > 0; off >>= 1) ls += __shfl_down(ls, off, 64);
  __shared__ float wsum[2];
  if ((t & 63) == 0) wsum[t >> 6] = ls;
  __syncthreads();
  if (t == 0) {
    rowsum[b] = wsum[0] + wsum[1];   // plain store, no atomics
    atomicAdd(&counts[idx], 1);      // int atomic: exact & commutative
  }
}

// ---------------- usage stats + deterministic loss reduction ----------------
__global__ void k_stats(const int* __restrict__ counts, const float* __restrict__ rowsum,
                        float* __restrict__ out_sc, int B, int K) {
  int t = threadIdx.x;
  double ent = 0.0, tot = 0.0, S = 0.0;
  int used = 0;
  for (int k = t; k < K; k += 256) {
    int c = counts[k];
    double u = (double)c / (double)B;
    ent += u * log(u + 1e-10);
    tot += u;
    used += (c > 0) ? 1 : 0;
  }
  for (int b = t; b < B; b += 256) S += (double)rowsum[b];
  __shared__ double se[256];
  __shared__ double st[256];
  __shared__ double ss[256];
  __shared__ int su[256];
  se[t] = ent; st[t] = tot; ss[t] = S; su[t] = used;
  __syncthreads();
  for (int s = 128; s > 0; s >>= 1) {
    if (t < s) { se[t] += se[t + s]; st[t] += st[t + s]; ss[t] += ss[t + s]; su[t] += su[t + s]; }
    __syncthreads();
  }
  if (t == 0) {
    double Sm = ss[0];
    double N = (double)B * (double)D_DIM;
    out_sc[0] = (float)(0.25 * Sm / N);      // commit_loss (BETA=0.25)
    out_sc[1] = (float)(Sm / N);             // codebook_loss
    out_sc[2] = (float)exp(-se[0]);          // perplexity
    out_sc[3] = (float)su[0];                // used_codes
    out_sc[4] = (float)(st[0] / (double)K);  // usage_mean
  }
}

extern "C" void kernel_launch(void* const* d_in, const int* in_sizes, int n_in,
                              void* d_out, int out_size, void* d_ws, size_t ws_size,
                              hipStream_t stream) {
  const float* A = (const float*)d_in[0];
  const float* E = (const float*)d_in[1];
  const int D = D_DIM;
  const int B = in_sizes[0] / D;  // 32768
  const int K = in_sizes[1] / D;  // 8192

  float* out = (float*)d_out;
  float* out_idx = out;
  float* out_z = out + B;
  float* out_sc = out + B + (size_t)B * D;

  char* ws = (char*)d_ws;
  float* a2 = (float*)ws;                                  // B*4
  float* e2 = (float*)(ws + (size_t)B * 4);                // K*4
  int* counts = (int*)(ws + (size_t)B * 4 + (size_t)K * 4);// K*4
  float* rowsum = (float*)(ws + (size_t)B * 4 + (size_t)K * 8);          // B*4
  int* idx_ws = (int*)(ws + (size_t)B * 8 + (size_t)K * 8);              // B*4

  k_init<<<(K + 255) / 256, 256, 0, stream>>>(counts, K);
  k_rowsq<<<(B + 3) / 4, 256, 0, stream>>>(A, a2, B);
  k_rowsq<<<(K + 3) / 4, 256, 0, stream>>>(E, e2, K);
  k_argmin<<<B / 128, 512, 0, stream>>>(A, E, a2, e2, out_idx, idx_ws, K);
  k_gather<<<B, 128, 0, stream>>>(A, E, idx_ws, out_z, rowsum, counts);
  k_stats<<<1, 256, 0, stream>>>(counts, rowsum, out_sc, B, K);
}